// Round 2
// 1075.608 us; speedup vs baseline: 1.0948x; 1.0948x over previous
//
#include <hip/hip_runtime.h>
#include <math.h>

#define VOCAB 50257
#define VPAD  50304      // 393*128
#define TLEN  2039
#define KROW  2048
#define NEMB  1024
#define DSTEP 128
#define MROWS 4096       // B*KROW
#define NBJ   786        // 393 tiles * 2 wave-chunks

typedef __attribute__((ext_vector_type(4))) float f32x4;
typedef __attribute__((ext_vector_type(8))) short s16x8;

__device__ __forceinline__ short f2bf(float f) {
  unsigned u = __float_as_uint(f);
  u += 0x7FFF + ((u >> 16) & 1);   // RNE
  return (short)(u >> 16);
}

__device__ __forceinline__ void async16(const void* g, void* l) {
  __builtin_amdgcn_global_load_lds((const __attribute__((address_space(1))) void*)g,
                                   (__attribute__((address_space(3))) void*)l, 16, 0, 0);
}

__device__ __forceinline__ f32x4 mfma16(s16x8 a, s16x8 b, f32x4 c) {
  return __builtin_amdgcn_mfma_f32_16x16x32_bf16(a, b, c, 0, 0, 0);
}

// ---------------------------------------------------------------------------
// prep: [0,4096) build x_bf rows; [4096,4352) transpose W_bb -> bf16;
//       [4352,10640) convert wte -> bf16 padded to VPAD rows
// ---------------------------------------------------------------------------
__global__ void prep_kernel(const float* __restrict__ noise, const float* __restrict__ leftn,
                            const float* __restrict__ rightn, const float* __restrict__ wte,
                            const float* __restrict__ wpe, const float* __restrict__ wbb,
                            const int* __restrict__ toks,
                            short* __restrict__ xbf, short* __restrict__ wbbT,
                            short* __restrict__ wtebf) {
  __shared__ float tile[64][65];
  int bid = blockIdx.x, t = threadIdx.x;
  if (bid < 4096) {
    int b = bid >> 11, k = bid & 2047;
    int e0 = t * 4, r = e0 >> 7, d = e0 & 127;
    int j = k + r;
    float4 v;
    if (j < 8) {
      v = *(const float4*)(leftn + (((size_t)b * 8 + j) * 8 + r) * 128 + d);
    } else if (j < 2047) {
      int tt = j - 8;
      float w = (float)(r + 1) * 0.125f;
      float4 nz = *(const float4*)(noise + (((size_t)b * TLEN + tt) * 8 + r) * 128 + d);
      int tok = toks[b * TLEN + tt];
      float4 em = *(const float4*)(wte + (size_t)tok * 128 + d);
      float iw = 1.0f - w;
      v.x = em.x * iw + nz.x * w; v.y = em.y * iw + nz.y * w;
      v.z = em.z * iw + nz.z * w; v.w = em.w * iw + nz.w * w;
    } else {
      v = *(const float4*)(rightn + (((size_t)b * 8 + (j - 2047)) * 8 + r) * 128 + d);
    }
    float4 pe = *(const float4*)(wpe + (size_t)k * NEMB + e0);
    short4 o;
    o.x = f2bf(v.x + pe.x); o.y = f2bf(v.y + pe.y);
    o.z = f2bf(v.z + pe.z); o.w = f2bf(v.w + pe.w);
    *(short4*)(xbf + (size_t)bid * NEMB + e0) = o;
  } else if (bid < 4352) {
    int tid = bid - 4096;
    int d0 = (tid >> 4) * 64, e0 = (tid & 15) * 64;
    int c = t & 63, g = t >> 6;
#pragma unroll
    for (int i = 0; i < 16; ++i) {
      int rr = g * 16 + i;
      tile[rr][c] = wbb[(size_t)(d0 + rr) * NEMB + e0 + c];
    }
    __syncthreads();
#pragma unroll
    for (int i = 0; i < 16; ++i) {
      int rr = g * 16 + i;
      wbbT[(size_t)(e0 + rr) * NEMB + d0 + c] = f2bf(tile[c][rr]);
    }
  } else {
    int tid = bid - 4352;                       // [0, 6288)
    size_t base = (size_t)tid * 1024 + t * 4;   // element in padded wte
    int row = (int)(base >> 7);
    short4 o;
    if (row < VOCAB) {
      float4 vv = *(const float4*)(wte + base);
      o.x = f2bf(vv.x); o.y = f2bf(vv.y); o.z = f2bf(vv.z); o.w = f2bf(vv.w);
    } else {
      o.x = 0; o.y = 0; o.z = 0; o.w = 0;
    }
    *(short4*)(wtebf + base) = o;
  }
}

// ---------------------------------------------------------------------------
// gemm1: new_x = tanh(x @ W_bb). M=4096 N=1024 K=1024. 128x128 tile, BK=64.
// A = xbf [m][k] row-major; B = wbbT [n][k] row-major (gemm_bt).
// XOR-swizzled LDS (granule^row) so global_load_lds contiguity holds and
// ds_read_b128 frag reads are bank-conflict-free.
// ---------------------------------------------------------------------------
__global__ __launch_bounds__(256) void gemm1_kernel(const short* __restrict__ xbf,
                                                    const short* __restrict__ wbbT,
                                                    float* __restrict__ newx,
                                                    short* __restrict__ topbf) {
  __shared__ short As[128 * 64];
  __shared__ short Bs[128 * 64];
  int t = threadIdx.x;
  int lane = t & 63, w = t >> 6;
  int wm = w >> 1, wn = w & 1;
  int quad = lane >> 4, l15 = lane & 15;
  int m0 = blockIdx.x * 128, n0 = blockIdx.y * 128;

  int rowS[4], gS[4];
#pragma unroll
  for (int i = 0; i < 4; ++i) {
    int lin = i * 256 + t;
    rowS[i] = lin >> 3;
    gS[i] = (lin & 7) ^ (rowS[i] & 7);
  }
  const short* aBase = xbf + (size_t)m0 * NEMB;
  const short* bBase = wbbT + (size_t)n0 * NEMB;

  f32x4 zero = {0.f, 0.f, 0.f, 0.f};
  f32x4 acc[4][4];
#pragma unroll
  for (int i = 0; i < 4; ++i)
#pragma unroll
    for (int j = 0; j < 4; ++j) acc[i][j] = zero;

  for (int kt = 0; kt < 16; ++kt) {
    int k0 = kt * 64;
#pragma unroll
    for (int i = 0; i < 4; ++i) {
      int lin = i * 256 + t;
      async16(aBase + (size_t)rowS[i] * NEMB + k0 + gS[i] * 8, &As[lin * 8]);
      async16(bBase + (size_t)rowS[i] * NEMB + k0 + gS[i] * 8, &Bs[lin * 8]);
    }
    __syncthreads();
#pragma unroll
    for (int kk = 0; kk < 2; ++kk) {
      int g = ((kk * 4 + quad) ^ (lane & 7)) * 8;
      s16x8 a[4], b[4];
#pragma unroll
      for (int mi = 0; mi < 4; ++mi)
        a[mi] = *(const s16x8*)&As[(wm * 64 + mi * 16 + l15) * 64 + g];
#pragma unroll
      for (int ni = 0; ni < 4; ++ni)
        b[ni] = *(const s16x8*)&Bs[(wn * 64 + ni * 16 + l15) * 64 + g];
#pragma unroll
      for (int mi = 0; mi < 4; ++mi)
#pragma unroll
        for (int ni = 0; ni < 4; ++ni)
          acc[mi][ni] = mfma16(a[mi], b[ni], acc[mi][ni]);
    }
    __syncthreads();
  }

  bool isTop = (blockIdx.y == 0);
#pragma unroll
  for (int mi = 0; mi < 4; ++mi) {
#pragma unroll
    for (int reg = 0; reg < 4; ++reg) {
      int mg = m0 + wm * 64 + mi * 16 + quad * 4 + reg;
      size_t ro = (size_t)mg * NEMB;
#pragma unroll
      for (int ni = 0; ni < 4; ++ni) {
        int ng = n0 + wn * 64 + ni * 16 + l15;
        float tv = tanhf(acc[mi][ni][reg]);
        newx[ro + ng] = tv;
        if (isTop) topbf[mg * DSTEP + ng] = f2bf(tv);
      }
    }
  }
}

// ---------------------------------------------------------------------------
// emb_loss partials: sum (new_x[:, :-1] - new_x[:, 1:])^2 per block -> embp[x]
// (no same-address atomics; final_kernel sums the array)
// ---------------------------------------------------------------------------
__global__ void emb_kernel(const float* __restrict__ newx, float* __restrict__ embp) {
  __shared__ float sred[4];
  int x = blockIdx.x;
  int b = x / 2047, k = x - b * 2047;
  const float* r0 = newx + ((size_t)b * KROW + k) * NEMB;
  int t = threadIdx.x;
  float4 a = *(const float4*)(r0 + t * 4);
  float4 c = *(const float4*)(r0 + NEMB + t * 4);
  float dx = a.x - c.x, dy = a.y - c.y, dz = a.z - c.z, dw = a.w - c.w;
  float s = dx * dx + dy * dy + dz * dz + dw * dw;
#pragma unroll
  for (int off = 32; off; off >>= 1) s += __shfl_xor(s, off);
  if ((t & 63) == 0) sred[t >> 6] = s;
  __syncthreads();
  if (t == 0) embp[x] = sred[0] + sred[1] + sred[2] + sred[3];
}

// ---------------------------------------------------------------------------
// gemm2: tok_logits = topmost @ wte^T + fused per-64-col softmax partials.
// M=4096, N=50304(padded), K=128 (single LDS stage, no K-loop barriers).
// Epilogue templated: FULL tiles (blockIdx.y<392) skip all col<VOCAB guards.
// ---------------------------------------------------------------------------
template <bool FULL>
__device__ __forceinline__ void gemm2_epilogue(const f32x4 (&acc)[4][4], int m0, int n0,
                                               int wm, int wn, int quad, int l15,
                                               float* __restrict__ out,
                                               float* __restrict__ pmax,
                                               float* __restrict__ psum) {
  int colBase = n0 + wn * 64 + l15;
  // --- store logits ---
#pragma unroll
  for (int mi = 0; mi < 4; ++mi) {
#pragma unroll
    for (int reg = 0; reg < 4; ++reg) {
      int mg = m0 + wm * 64 + mi * 16 + quad * 4 + reg;
      size_t ro = (size_t)mg * VOCAB;
#pragma unroll
      for (int ni = 0; ni < 4; ++ni) {
        int col = colBase + ni * 16;
        if (FULL || col < VOCAB) out[ro + col] = acc[mi][ni][reg];
      }
    }
  }

  // --- fused softmax partials per 64-col chunk ---
  int jj = (n0 >> 6) + wn;   // == blockIdx.y*2 + wn
  bool valid[4];
  if (!FULL) {
#pragma unroll
    for (int ni = 0; ni < 4; ++ni) valid[ni] = (colBase + ni * 16) < VOCAB;
  }
#pragma unroll
  for (int mi = 0; mi < 4; ++mi) {
#pragma unroll
    for (int reg = 0; reg < 4; ++reg) {
      float v0 = acc[mi][0][reg], v1 = acc[mi][1][reg];
      float v2 = acc[mi][2][reg], v3 = acc[mi][3][reg];
      float rmax, s;
      if (FULL) {
        rmax = fmaxf(fmaxf(v0, v1), fmaxf(v2, v3));
      } else {
        rmax = -3.0e38f;
        if (valid[0]) rmax = fmaxf(rmax, v0);
        if (valid[1]) rmax = fmaxf(rmax, v1);
        if (valid[2]) rmax = fmaxf(rmax, v2);
        if (valid[3]) rmax = fmaxf(rmax, v3);
      }
#pragma unroll
      for (int off = 1; off <= 8; off <<= 1) rmax = fmaxf(rmax, __shfl_xor(rmax, off));
      if (FULL) {
        s = __expf(v0 - rmax) + __expf(v1 - rmax) + __expf(v2 - rmax) + __expf(v3 - rmax);
      } else {
        s = 0.f;
        if (valid[0]) s += __expf(v0 - rmax);
        if (valid[1]) s += __expf(v1 - rmax);
        if (valid[2]) s += __expf(v2 - rmax);
        if (valid[3]) s += __expf(v3 - rmax);
      }
#pragma unroll
      for (int off = 1; off <= 8; off <<= 1) s += __shfl_xor(s, off);
      if (l15 == 0) {
        int mg = m0 + wm * 64 + mi * 16 + quad * 4 + reg;
        pmax[mg * NBJ + jj] = rmax;
        psum[mg * NBJ + jj] = s;
      }
    }
  }
}

__global__ __launch_bounds__(256, 2) void gemm2_kernel(const short* __restrict__ topbf,
                                                       const short* __restrict__ wtebf,
                                                       float* __restrict__ out,
                                                       float* __restrict__ pmax,
                                                       float* __restrict__ psum) {
  __shared__ short As[128 * 128];
  __shared__ short Bs[128 * 128];
  int t = threadIdx.x;
  int lane = t & 63, w = t >> 6;
  int wm = w >> 1, wn = w & 1;
  int quad = lane >> 4, l15 = lane & 15;
  int m0 = blockIdx.x * 128, n0 = blockIdx.y * 128;

  const short* aB = topbf + (size_t)m0 * DSTEP;
  const short* bB = wtebf + (size_t)n0 * DSTEP;
#pragma unroll
  for (int i = 0; i < 8; ++i) {
    int lin = i * 256 + t;
    int row = lin >> 4;
    int g = (lin & 15) ^ (row & 15);
    async16(aB + (size_t)row * DSTEP + g * 8, &As[lin * 8]);
    async16(bB + (size_t)row * DSTEP + g * 8, &Bs[lin * 8]);
  }
  f32x4 zero = {0.f, 0.f, 0.f, 0.f};
  f32x4 acc[4][4];
#pragma unroll
  for (int i = 0; i < 4; ++i)
#pragma unroll
    for (int j = 0; j < 4; ++j) acc[i][j] = zero;
  __syncthreads();

#pragma unroll
  for (int ks = 0; ks < 4; ++ks) {
    int g = ((ks * 4 + quad) ^ l15) * 8;
    s16x8 a[4], b[4];
#pragma unroll
    for (int mi = 0; mi < 4; ++mi)
      a[mi] = *(const s16x8*)&As[(wm * 64 + mi * 16 + l15) * 128 + g];
#pragma unroll
    for (int ni = 0; ni < 4; ++ni)
      b[ni] = *(const s16x8*)&Bs[(wn * 64 + ni * 16 + l15) * 128 + g];
#pragma unroll
    for (int mi = 0; mi < 4; ++mi)
#pragma unroll
      for (int ni = 0; ni < 4; ++ni)
        acc[mi][ni] = mfma16(a[mi], b[ni], acc[mi][ni]);
  }

  if (blockIdx.y != 392) {
    gemm2_epilogue<true>(acc, m0, n0, wm, wn, quad, l15, out, pmax, psum);
  } else {
    gemm2_epilogue<false>(acc, m0, n0, wm, wn, quad, l15, out, pmax, psum);
  }
}

// ---------------------------------------------------------------------------
// reduce: per pred row combine 786 partials -> logsumexp, gather target logit.
// Writes per-row nll to array (no same-address atomics).
// ---------------------------------------------------------------------------
__global__ void reduce_kernel(const float* __restrict__ pmax, const float* __restrict__ psum,
                              const float* __restrict__ out, const int* __restrict__ toks,
                              float* __restrict__ nll) {
  __shared__ float sred[4];
  __shared__ float sM;
  int p = blockIdx.x;                     // [0, 4078)
  int b = p / TLEN, i = p - b * TLEN;
  size_t m = (size_t)b * KROW + i + 8;
  const float* pm = pmax + m * NBJ;
  const float* ps = psum + m * NBJ;
  int t = threadIdx.x;
  float lm = -3.0e38f;
  for (int j = t; j < NBJ; j += 256) lm = fmaxf(lm, pm[j]);
#pragma unroll
  for (int off = 32; off; off >>= 1) lm = fmaxf(lm, __shfl_xor(lm, off));
  if ((t & 63) == 0) sred[t >> 6] = lm;
  __syncthreads();
  if (t == 0) sM = fmaxf(fmaxf(sred[0], sred[1]), fmaxf(sred[2], sred[3]));
  __syncthreads();
  float M = sM;
  float ls = 0.f;
  for (int j = t; j < NBJ; j += 256) ls += ps[j] * __expf(pm[j] - M);
#pragma unroll
  for (int off = 32; off; off >>= 1) ls += __shfl_xor(ls, off);
  if ((t & 63) == 0) sred[t >> 6] = ls;
  __syncthreads();
  if (t == 0) {
    float S = sred[0] + sred[1] + sred[2] + sred[3];
    float lse = M + logf(S);
    nll[p] = lse - out[m * VOCAB + toks[p]];
  }
}

// ---------------------------------------------------------------------------
// final: sum emb partials (4094) and nll (4078), combine into loss scalar
// ---------------------------------------------------------------------------
__global__ void final_kernel(const float* __restrict__ embp, const float* __restrict__ nll,
                             float* __restrict__ out) {
  __shared__ float sa[4], sb[4];
  int t = threadIdx.x;
  float a = 0.f, b = 0.f;
  for (int i = t; i < 4094; i += 256) a += embp[i];
  for (int i = t; i < 4078; i += 256) b += nll[i];
#pragma unroll
  for (int off = 32; off; off >>= 1) {
    a += __shfl_xor(a, off);
    b += __shfl_xor(b, off);
  }
  if ((t & 63) == 0) { sa[t >> 6] = a; sb[t >> 6] = b; }
  __syncthreads();
  if (t == 0) {
    float A = sa[0] + sa[1] + sa[2] + sa[3];
    float B = sb[0] + sb[1] + sb[2] + sb[3];
    out[(size_t)MROWS * VOCAB] = B / 4078.0f + A / (2.0f * 2047.0f * 1024.0f);
  }
}

// ---------------------------------------------------------------------------
extern "C" void kernel_launch(void* const* d_in, const int* in_sizes, int n_in,
                              void* d_out, int out_size, void* d_ws, size_t ws_size,
                              hipStream_t stream) {
  const float* noise  = (const float*)d_in[0];
  const float* leftn  = (const float*)d_in[1];
  const float* rightn = (const float*)d_in[2];
  const float* wte    = (const float*)d_in[3];
  const float* wpe    = (const float*)d_in[4];
  const float* wbb    = (const float*)d_in[5];
  const int*   toks   = (const int*)d_in[6];
  float* out = (float*)d_out;
  char* ws = (char*)d_ws;

  short* xbf   = (short*)(ws + 0);           //  8,388,608  (4096x1024 bf16)
  short* wbbT  = (short*)(ws + 8388608);     //  2,097,152  (1024x1024 bf16, transposed)
  short* wtebf = (short*)(ws + 10485760);    // 12,877,824  (50304x128 bf16)
  float* newx  = (float*)(ws + 23363584);    // 16,777,216  (4096x1024 f32)
  short* topbf = (short*)(ws + 40140800);    //  1,048,576  (4096x128 bf16)
  float* pmax  = (float*)(ws + 41189376);    // 12,877,824  (4096x786 f32)
  float* psum  = (float*)(ws + 54067200);    // 12,877,824
  float* embp  = (float*)(ws + 66945024);    // 16,384     (4094 f32 partials)
  float* nll   = (float*)(ws + 66961408);    // 16,312     (4078 f32 per-row nll)

  prep_kernel<<<10640, 256, 0, stream>>>(noise, leftn, rightn, wte, wpe, wbb, toks,
                                         xbf, wbbT, wtebf);
  gemm1_kernel<<<dim3(32, 8), 256, 0, stream>>>(xbf, wbbT, newx, topbf);
  emb_kernel<<<4094, 256, 0, stream>>>(newx, embp);
  gemm2_kernel<<<dim3(32, 393), 256, 0, stream>>>(topbf, wtebf, out, pmax, psum);
  reduce_kernel<<<4078, 256, 0, stream>>>(pmax, psum, out, toks, nll);
  final_kernel<<<1, 256, 0, stream>>>(embp, nll, out);
}